// Round 1
// baseline (571.614 us; speedup 1.0000x reference)
//
#include <hip/hip_runtime.h>

#define FDIM 256
#define CHUNK 64
#define T_STEPS 8
#define LR_X 0.1f

// ---- CSR build ------------------------------------------------------------

__global__ void k_count(const int* __restrict__ dst, int* __restrict__ cnt, int E) {
    int e = blockIdx.x * blockDim.x + threadIdx.x;
    if (e < E) atomicAdd(&cnt[dst[e]], 1);
}

// Exclusive scan of counts (in cntcur[0..n-1]) -> start[0..n] and back into
// cntcur (cursor for the fill kernel). Single block; reads of chunk k happen
// before writes of chunk k (guarded by __syncthreads), chunks are disjoint.
__global__ __launch_bounds__(1024) void k_scan(int* cntcur, int* start, int n) {
    __shared__ int sdata[1024];
    int running = 0;
    for (int base = 0; base < n + 1; base += 1024) {
        int i = base + (int)threadIdx.x;
        int v = (i < n) ? cntcur[i] : 0;
        sdata[threadIdx.x] = v;
        __syncthreads();
        for (int off = 1; off < 1024; off <<= 1) {
            int t = ((int)threadIdx.x >= off) ? sdata[threadIdx.x - off] : 0;
            __syncthreads();
            sdata[threadIdx.x] += t;
            __syncthreads();
        }
        int incl = sdata[threadIdx.x];
        int total = sdata[1023];
        if (i <= n) {
            int excl = running + incl - v;
            start[i] = excl;
            if (i < n) cntcur[i] = excl;
        }
        running += total;
        __syncthreads();
    }
}

// Scatter edges into CSR slots; also gathers the step-invariant edge weight
// w[src*N + dst]. Slot order within a row is nondeterministic (atomic), fixed
// by k_sort below.
__global__ void k_fill(const int* __restrict__ src, const int* __restrict__ dst,
                       const float* __restrict__ w, int* __restrict__ cursor,
                       int* __restrict__ col, float* __restrict__ wv,
                       int* __restrict__ eid, int E, int N) {
    int e = blockIdx.x * blockDim.x + threadIdx.x;
    if (e >= E) return;
    int s = src[e], d = dst[e];
    int p = atomicAdd(&cursor[d], 1);
    col[p] = s;
    wv[p]  = w[(size_t)s * N + d];
    eid[p] = e;
}

// Deterministic order: insertion-sort each row by original edge id.
__global__ void k_sort(int* __restrict__ col, float* __restrict__ wv,
                       int* __restrict__ eid, const int* __restrict__ start, int n) {
    int r = blockIdx.x * blockDim.x + threadIdx.x;
    if (r >= n) return;
    int s = start[r], e = start[r + 1];
    for (int i = s + 1; i < e; ++i) {
        int ke = eid[i]; int kc = col[i]; float kw = wv[i];
        int j = i - 1;
        while (j >= s && eid[j] > ke) {
            eid[j + 1] = eid[j]; col[j + 1] = col[j]; wv[j + 1] = wv[j]; --j;
        }
        eid[j + 1] = ke; col[j + 1] = kc; wv[j + 1] = kw;
    }
}

// vals (working copy in d_out) = values; th = tanh(values)
__global__ void k_init(const float* __restrict__ vin, float* __restrict__ vals,
                       float* __restrict__ th, int n) {
    int i = blockIdx.x * blockDim.x + threadIdx.x;
    if (i < n) {
        float v = vin[i];
        vals[i] = v;
        th[i] = tanhf(v);
    }
}

// ---- Per-step kernels -----------------------------------------------------

// One block per dst row d (all N rows). thread f = feature f.
// pred = sum_e w_e * th[col_e][f]; err = vals - pred; dd = 1 - tanh(err)^2
__global__ __launch_bounds__(FDIM) void k_pred_err(
    const int* __restrict__ start, const int* __restrict__ col,
    const float* __restrict__ wv, const float* __restrict__ vals,
    const float* __restrict__ th, float* __restrict__ err,
    float* __restrict__ dd) {
    const int d = blockIdx.x;
    const int f = threadIdx.x;
    const int s = start[d], e = start[d + 1];
    __shared__ int   s_col[CHUNK];
    __shared__ float s_w[CHUNK];
    float acc = 0.f;
    for (int base = s; base < e; base += CHUNK) {
        const int cnt = min(CHUNK, e - base);
        if (f < cnt) {
            s_col[f] = col[base + f] * FDIM;
            s_w[f]   = wv[base + f];
        }
        __syncthreads();
        for (int j = 0; j < cnt; ++j)
            acc = fmaf(s_w[j], th[s_col[j] + f], acc);
        __syncthreads();
    }
    const int idx = d * FDIM + f;
    const float er = vals[idx] - acc;
    err[idx] = er;
    const float u = tanhf(er);
    dd[idx] = 1.f - u * u;
}

// One block per INTERNAL dst row d (< NI).
// g = sum_e w_e * dd[col_e][f]; vals[d] -= lr*(err[d]-g); th[d] = tanh(vals[d])
__global__ __launch_bounds__(FDIM) void k_grad_update(
    const int* __restrict__ start, const int* __restrict__ col,
    const float* __restrict__ wv, const float* __restrict__ err,
    const float* __restrict__ dd, float* __restrict__ vals,
    float* __restrict__ th) {
    const int d = blockIdx.x;
    const int f = threadIdx.x;
    const int s = start[d], e = start[d + 1];
    __shared__ int   s_col[CHUNK];
    __shared__ float s_w[CHUNK];
    float g = 0.f;
    for (int base = s; base < e; base += CHUNK) {
        const int cnt = min(CHUNK, e - base);
        if (f < cnt) {
            s_col[f] = col[base + f] * FDIM;
            s_w[f]   = wv[base + f];
        }
        __syncthreads();
        for (int j = 0; j < cnt; ++j)
            g = fmaf(s_w[j], dd[s_col[j] + f], g);
        __syncthreads();
    }
    const int idx = d * FDIM + f;
    const float nv = vals[idx] - LR_X * (err[idx] - g);
    vals[idx] = nv;
    th[idx] = tanhf(nv);
}

// ---- Launch ---------------------------------------------------------------

extern "C" void kernel_launch(void* const* d_in, const int* in_sizes, int n_in,
                              void* d_out, int out_size, void* d_ws, size_t ws_size,
                              hipStream_t stream) {
    const float* values = (const float*)d_in[0];
    const float* w      = (const float*)d_in[1];
    const int*   edge   = (const int*)d_in[2];
    const int NF = in_sizes[0];            // N*F
    const int N  = NF / FDIM;              // 5000
    const int E  = in_sizes[2] / 2;        // 160000
    const int NI = in_sizes[3];            // 2500
    const int* srcp = edge;
    const int* dstp = edge + E;
    float* vals = (float*)d_out;           // working values live in d_out

    char* ws = (char*)d_ws;
    size_t off = 0;
    auto alloc = [&](size_t bytes) {
        void* p = ws + off;
        off = (off + bytes + 255) & ~(size_t)255;
        return p;
    };
    int*   start = (int*)  alloc((size_t)(N + 1) * sizeof(int));
    int*   cur   = (int*)  alloc((size_t)N * sizeof(int));
    int*   col   = (int*)  alloc((size_t)E * sizeof(int));
    float* wv    = (float*)alloc((size_t)E * sizeof(float));
    int*   eid   = (int*)  alloc((size_t)E * sizeof(int));
    float* th    = (float*)alloc((size_t)NF * sizeof(float));
    float* err   = (float*)alloc((size_t)NF * sizeof(float));
    float* dd    = (float*)alloc((size_t)NF * sizeof(float));
    (void)ws_size; (void)n_in; (void)out_size;

    hipMemsetAsync(cur, 0, (size_t)N * sizeof(int), stream);
    const int gE = (E + 255) / 256;
    k_count<<<gE, 256, 0, stream>>>(dstp, cur, E);
    k_scan<<<1, 1024, 0, stream>>>(cur, start, N);
    k_fill<<<gE, 256, 0, stream>>>(srcp, dstp, w, cur, col, wv, eid, E, N);
    k_sort<<<(N + 255) / 256, 256, 0, stream>>>(col, wv, eid, start, N);
    k_init<<<(NF + 255) / 256, 256, 0, stream>>>(values, vals, th, NF);

    for (int t = 0; t < T_STEPS; ++t) {
        k_pred_err<<<N, FDIM, 0, stream>>>(start, col, wv, vals, th, err, dd);
        k_grad_update<<<NI, FDIM, 0, stream>>>(start, col, wv, err, dd, vals, th);
    }
}

// Round 2
// 293.212 us; speedup vs baseline: 1.9495x; 1.9495x over previous
//
#include <hip/hip_runtime.h>

#define FDIM 256
#define CHUNK 64
#define T_STEPS 8
#define LR_X 0.1f

// ---- CSR build ------------------------------------------------------------

__global__ void k_count(const int* __restrict__ dst, int* __restrict__ cnt, int E) {
    int e = blockIdx.x * blockDim.x + threadIdx.x;
    if (e < E) atomicAdd(&cnt[dst[e]], 1);
}

// Exclusive scan of counts (in cntcur[0..n-1]) -> start[0..n] and back into
// cntcur (cursor for the fill kernel). Single block.
__global__ __launch_bounds__(1024) void k_scan(int* cntcur, int* start, int n) {
    __shared__ int sdata[1024];
    int running = 0;
    for (int base = 0; base < n + 1; base += 1024) {
        int i = base + (int)threadIdx.x;
        int v = (i < n) ? cntcur[i] : 0;
        sdata[threadIdx.x] = v;
        __syncthreads();
        for (int off = 1; off < 1024; off <<= 1) {
            int t = ((int)threadIdx.x >= off) ? sdata[threadIdx.x - off] : 0;
            __syncthreads();
            sdata[threadIdx.x] += t;
            __syncthreads();
        }
        int incl = sdata[threadIdx.x];
        int total = sdata[1023];
        if (i <= n) {
            int excl = running + incl - v;
            start[i] = excl;
            if (i < n) cntcur[i] = excl;
        }
        running += total;
        __syncthreads();
    }
}

// Scatter edge ids into CSR slots (order within a row nondeterministic; fixed
// deterministically by k_rank_scatter below).
__global__ void k_fill_slots(const int* __restrict__ dst, int* __restrict__ cursor,
                             int* __restrict__ eidT, int E) {
    int e = blockIdx.x * blockDim.x + threadIdx.x;
    if (e >= E) return;
    int p = atomicAdd(&cursor[dst[e]], 1);
    eidT[p] = e;
}

// One WAVE per dst row. Lane handles elements i = s+lane, s+lane+64, ...
// rank(i) = #{j in row : eid[j] < eid[i]}  (eids unique -> total order).
// Writes col/wv at the deterministic slot s+rank; gathers w[src,dst] here.
__global__ __launch_bounds__(256) void k_rank_scatter(
    const int* __restrict__ eidT, const int* __restrict__ start,
    const int* __restrict__ src, const float* __restrict__ w,
    int* __restrict__ col, float* __restrict__ wv, int nRows, int N) {
    const int wid  = (int)((blockIdx.x * blockDim.x + threadIdx.x) >> 6);
    const int lane = (int)(threadIdx.x & 63);
    if (wid >= nRows) return;
    const int s = start[wid], e = start[wid + 1];
    for (int i = s + lane; i < e; i += 64) {
        const int myeid = eidT[i];
        int rank = 0;
        for (int j = s; j < e; ++j)
            rank += (eidT[j] < myeid) ? 1 : 0;
        const int pos = s + rank;
        const int sc  = src[myeid];
        col[pos] = sc * FDIM;
        wv[pos]  = w[(size_t)sc * N + wid];
    }
}

// vals (working copy in d_out) = values; th = tanh(values)
__global__ void k_init(const float* __restrict__ vin, float* __restrict__ vals,
                       float* __restrict__ th, int n) {
    int i = blockIdx.x * blockDim.x + threadIdx.x;
    if (i < n) {
        float v = vin[i];
        vals[i] = v;
        th[i] = tanhf(v);
    }
}

// ---- Per-step kernels -----------------------------------------------------

// One block per dst row d (all N rows). thread f = feature f.
// pred = sum_e w_e * th[col_e][f]; err = vals - pred; dd = 1 - tanh(err)^2
__global__ __launch_bounds__(FDIM) void k_pred_err(
    const int* __restrict__ start, const int* __restrict__ col,
    const float* __restrict__ wv, const float* __restrict__ vals,
    const float* __restrict__ th, float* __restrict__ err,
    float* __restrict__ dd) {
    const int d = blockIdx.x;
    const int f = threadIdx.x;
    const int s = start[d], e = start[d + 1];
    __shared__ int   s_col[CHUNK];
    __shared__ float s_w[CHUNK];
    float acc = 0.f;
    for (int base = s; base < e; base += CHUNK) {
        const int cnt = min(CHUNK, e - base);
        if (f < cnt) {
            s_col[f] = col[base + f];
            s_w[f]   = wv[base + f];
        }
        __syncthreads();
        for (int j = 0; j < cnt; ++j)
            acc = fmaf(s_w[j], th[s_col[j] + f], acc);
        __syncthreads();
    }
    const int idx = d * FDIM + f;
    const float er = vals[idx] - acc;
    err[idx] = er;
    const float u = tanhf(er);
    dd[idx] = 1.f - u * u;
}

// One block per INTERNAL dst row d (< NI).
// g = sum_e w_e * dd[col_e][f]; vals[d] -= lr*(err[d]-g); th[d] = tanh(vals[d])
__global__ __launch_bounds__(FDIM) void k_grad_update(
    const int* __restrict__ start, const int* __restrict__ col,
    const float* __restrict__ wv, const float* __restrict__ err,
    const float* __restrict__ dd, float* __restrict__ vals,
    float* __restrict__ th) {
    const int d = blockIdx.x;
    const int f = threadIdx.x;
    const int s = start[d], e = start[d + 1];
    __shared__ int   s_col[CHUNK];
    __shared__ float s_w[CHUNK];
    float g = 0.f;
    for (int base = s; base < e; base += CHUNK) {
        const int cnt = min(CHUNK, e - base);
        if (f < cnt) {
            s_col[f] = col[base + f];
            s_w[f]   = wv[base + f];
        }
        __syncthreads();
        for (int j = 0; j < cnt; ++j)
            g = fmaf(s_w[j], dd[s_col[j] + f], g);
        __syncthreads();
    }
    const int idx = d * FDIM + f;
    const float nv = vals[idx] - LR_X * (err[idx] - g);
    vals[idx] = nv;
    th[idx] = tanhf(nv);
}

// ---- Launch ---------------------------------------------------------------

extern "C" void kernel_launch(void* const* d_in, const int* in_sizes, int n_in,
                              void* d_out, int out_size, void* d_ws, size_t ws_size,
                              hipStream_t stream) {
    const float* values = (const float*)d_in[0];
    const float* w      = (const float*)d_in[1];
    const int*   edge   = (const int*)d_in[2];
    const int NF = in_sizes[0];            // N*F
    const int N  = NF / FDIM;              // 5000
    const int E  = in_sizes[2] / 2;        // 160000
    const int NI = in_sizes[3];            // 2500
    const int* srcp = edge;
    const int* dstp = edge + E;
    float* vals = (float*)d_out;           // working values live in d_out

    char* ws = (char*)d_ws;
    size_t off = 0;
    auto alloc = [&](size_t bytes) {
        void* p = ws + off;
        off = (off + bytes + 255) & ~(size_t)255;
        return p;
    };
    int*   start = (int*)  alloc((size_t)(N + 1) * sizeof(int));
    int*   cur   = (int*)  alloc((size_t)N * sizeof(int));
    int*   eidT  = (int*)  alloc((size_t)E * sizeof(int));
    int*   col   = (int*)  alloc((size_t)E * sizeof(int));   // pre-scaled by FDIM
    float* wv    = (float*)alloc((size_t)E * sizeof(float));
    float* th    = (float*)alloc((size_t)NF * sizeof(float));
    float* err   = (float*)alloc((size_t)NF * sizeof(float));
    float* dd    = (float*)alloc((size_t)NF * sizeof(float));
    (void)ws_size; (void)n_in; (void)out_size;

    hipMemsetAsync(cur, 0, (size_t)N * sizeof(int), stream);
    const int gE = (E + 255) / 256;
    k_count<<<gE, 256, 0, stream>>>(dstp, cur, E);
    k_scan<<<1, 1024, 0, stream>>>(cur, start, N);
    k_fill_slots<<<gE, 256, 0, stream>>>(dstp, cur, eidT, E);
    // one wave per row -> 4 rows per 256-thread block
    k_rank_scatter<<<(N + 3) / 4, 256, 0, stream>>>(eidT, start, srcp, w, col, wv, N, N);
    k_init<<<(NF + 255) / 256, 256, 0, stream>>>(values, vals, th, NF);

    for (int t = 0; t < T_STEPS; ++t) {
        k_pred_err<<<N, FDIM, 0, stream>>>(start, col, wv, vals, th, err, dd);
        k_grad_update<<<NI, FDIM, 0, stream>>>(start, col, wv, err, dd, vals, th);
    }
}